// Round 1
// baseline (930.977 us; speedup 1.0000x reference)
//
#include <hip/hip_runtime.h>
#include <stdint.h>

#define N_NODES 50000
#define N_EDGES 800000
#define EDGE_F  96
#define NODE_F  256
#define GLOB_F  64
#define HIDDEN  1024
#define MLP_IN  608           // 256 + 3*96 + 64
#define M_PAD   50048         // 391 * 128, padded row count for GEMM tiles

typedef __bf16 bf16;
typedef __bf16 bf16x8 __attribute__((ext_vector_type(8)));
typedef float  f32x4  __attribute__((ext_vector_type(4)));

typedef __attribute__((address_space(1))) unsigned int gu32;
typedef __attribute__((address_space(3))) unsigned int lu32;

__device__ __forceinline__ void glds16(const void* g, void* l) {
    // async global->LDS, 16B per lane; LDS dest is wave-uniform base + lane*16
    __builtin_amdgcn_global_load_lds((const gu32*)g, (lu32*)l, 16, 0, 0);
}

// ---------------- workspace layout (bytes) ----------------
static constexpr size_t H_OFF    = 0;
static constexpr size_t H_BYTES  = (size_t)M_PAD * MLP_IN * 2;     // 60,858,368
static constexpr size_t HID_OFF  = H_OFF + H_BYTES;
static constexpr size_t HID_BYTES= (size_t)M_PAD * HIDDEN * 2;     // 102,498,304
static constexpr size_t W1T_OFF  = HID_OFF + HID_BYTES;
static constexpr size_t W1T_BYTES= (size_t)HIDDEN * MLP_IN * 2;
static constexpr size_t W2T_OFF  = W1T_OFF + W1T_BYTES;
static constexpr size_t W2T_BYTES= (size_t)NODE_F * HIDDEN * 2;
static constexpr size_t DEG_OFF  = W2T_OFF + W2T_BYTES;
static constexpr size_t DEG_BYTES= 200192;                          // 50000*4 padded
static constexpr size_t CUR_OFF  = DEG_OFF + DEG_BYTES;
static constexpr size_t CUR_BYTES= 200192;
static constexpr size_t START_OFF= CUR_OFF + CUR_BYTES;
static constexpr size_t START_BYTES = 200192;                       // 50001*4 padded
static constexpr size_t EIDS_OFF = START_OFF + START_BYTES;
static constexpr size_t EIDS_BYTES = (size_t)N_EDGES * 4;
static constexpr size_t WS_NEED  = EIDS_OFF + EIDS_BYTES;           // ~169 MB

// ---------------- CSR build ----------------
__global__ __launch_bounds__(256) void hist_kernel(const int* __restrict__ col,
                                                   int* __restrict__ deg) {
    int e = blockIdx.x * 256 + threadIdx.x;
    if (e < N_EDGES) atomicAdd(&deg[col[e]], 1);
}

__global__ __launch_bounds__(1024) void scan_kernel(const int* __restrict__ deg,
                                                    int* __restrict__ start) {
    __shared__ int partial[1024];
    const int t = threadIdx.x;
    const int CH = 49;                       // 1024*49 = 50176 >= 50000
    int base = t * CH;
    int s = 0;
    for (int i = 0; i < CH; i++) {
        int idx = base + i;
        if (idx < N_NODES) s += deg[idx];
    }
    partial[t] = s;
    __syncthreads();
    for (int off = 1; off < 1024; off <<= 1) {
        int v = (t >= off) ? partial[t - off] : 0;
        __syncthreads();
        partial[t] += v;
        __syncthreads();
    }
    int run = (t == 0) ? 0 : partial[t - 1];
    for (int i = 0; i < CH; i++) {
        int idx = base + i;
        if (idx < N_NODES) { start[idx] = run; run += deg[idx]; }
    }
    if (t == 1023) start[N_NODES] = run;     // == N_EDGES
}

__global__ __launch_bounds__(256) void scatter_kernel(const int* __restrict__ col,
                                                      const int* __restrict__ start,
                                                      int* __restrict__ cursor,
                                                      int* __restrict__ eids) {
    int e = blockIdx.x * 256 + threadIdx.x;
    if (e < N_EDGES) {
        int c = col[e];
        int p = start[c] + atomicAdd(&cursor[c], 1);
        eids[p] = e;
    }
}

// ---------------- build H = [x | sum | max | mean | u[batch]] in bf16 ----------------
__global__ __launch_bounds__(128) void build_h_kernel(const float* __restrict__ x,
                                                      const float* __restrict__ edge_attr,
                                                      const float* __restrict__ u,
                                                      const int* __restrict__ batch,
                                                      const int* __restrict__ start,
                                                      const int* __restrict__ eids,
                                                      bf16* __restrict__ H) {
    const int n = blockIdx.x;
    const int t = threadIdx.x;
    bf16* row = H + (size_t)n * MLP_IN;
    if (n >= N_NODES) {                       // pad rows -> zeros
        for (int c = t; c < MLP_IN; c += 128) row[c] = (bf16)0.0f;
        return;
    }
    const float* xr = x + (size_t)n * NODE_F;
    for (int c = t; c < NODE_F; c += 128) row[c] = (bf16)xr[c];
    if (t < GLOB_F) {
        int g = batch[n];
        row[544 + t] = (bf16)u[g * GLOB_F + t];
    }
    if (t < EDGE_F) {
        int s0 = start[n], s1 = start[n + 1];
        float sm = 0.0f, mx = -3.0e38f;
        for (int i = s0; i < s1; i++) {
            float v = edge_attr[(size_t)eids[i] * EDGE_F + t];
            sm += v;
            mx = fmaxf(mx, v);
        }
        int d = s1 - s0;
        if (d == 0) mx = 0.0f;
        float mean = sm / fmaxf((float)d, 1.0f);
        row[256 + t] = (bf16)sm;
        row[352 + t] = (bf16)mx;
        row[448 + t] = (bf16)mean;
    }
}

// ---------------- weights: fp32 [K][N] -> bf16 transposed [N][K] ----------------
__global__ __launch_bounds__(256) void convert_w_kernel(const float* __restrict__ W1,
                                                        const float* __restrict__ W2,
                                                        bf16* __restrict__ W1t,
                                                        bf16* __restrict__ W2t) {
    int i = blockIdx.x * 256 + threadIdx.x;
    if (i < HIDDEN * MLP_IN) {                // W1t[n][k] = W1[k][n]
        int n = i / MLP_IN, k = i - n * MLP_IN;
        W1t[i] = (bf16)W1[(size_t)k * HIDDEN + n];
    }
    if (i < NODE_F * HIDDEN) {                // W2t[n][k] = W2[k][n]
        int n = i / HIDDEN, k = i - n * HIDDEN;
        W2t[i] = (bf16)W2[(size_t)k * NODE_F + n];
    }
}

// ---------------- GEMM1: hid = relu(H @ W1 + b1), bf16 out ----------------
// 128x128 tile, BK=32, 4 waves of 64x64, 16x16x32 bf16 MFMA, B^T layout
__global__ __launch_bounds__(256) void gemm1_kernel(const bf16* __restrict__ H,
                                                    const bf16* __restrict__ Wt,
                                                    const float* __restrict__ b1,
                                                    bf16* __restrict__ hid) {
    __shared__ __align__(16) bf16 As[128 * 32];
    __shared__ __align__(16) bf16 Bs[128 * 32];
    const int t = threadIdx.x;
    const int wave = t >> 6, lane = t & 63;
    const int quad = lane >> 4, l16 = lane & 15;
    const int wm = (wave & 1) << 6, wn = (wave >> 1) << 6;
    const int bm = blockIdx.x, bn = blockIdx.y;

    f32x4 acc[4][4] = {};

    const char* Ag = (const char*)H  + (size_t)bm * 128 * (MLP_IN * 2);
    const char* Bg = (const char*)Wt + (size_t)bn * 128 * (MLP_IN * 2);
    const int srow = t >> 2, scc = t & 3;
    const size_t rowoff = (size_t)srow * (MLP_IN * 2) + scc * 16;
    char* Al = (char*)As + t * 16;
    char* Bl = (char*)Bs + t * 16;

    for (int k0 = 0; k0 < MLP_IN; k0 += 32) {
        __syncthreads();
        const char* a0 = Ag + rowoff + k0 * 2;
        glds16(a0, Al);
        glds16(a0 + (size_t)64 * (MLP_IN * 2), Al + 4096);
        const char* b0 = Bg + rowoff + k0 * 2;
        glds16(b0, Bl);
        glds16(b0 + (size_t)64 * (MLP_IN * 2), Bl + 4096);
        __syncthreads();
        bf16x8 a[4], b[4];
#pragma unroll
        for (int i = 0; i < 4; i++) a[i] = *(const bf16x8*)&As[(wm + i * 16 + l16) * 32 + quad * 8];
#pragma unroll
        for (int i = 0; i < 4; i++) b[i] = *(const bf16x8*)&Bs[(wn + i * 16 + l16) * 32 + quad * 8];
#pragma unroll
        for (int i = 0; i < 4; i++)
#pragma unroll
            for (int j = 0; j < 4; j++)
                acc[i][j] = __builtin_amdgcn_mfma_f32_16x16x32_bf16(a[i], b[j], acc[i][j], 0, 0, 0);
    }
#pragma unroll
    for (int i = 0; i < 4; i++) {
        int row0 = bm * 128 + wm + i * 16 + quad * 4;
#pragma unroll
        for (int j = 0; j < 4; j++) {
            int col = bn * 128 + wn + j * 16 + l16;
            float bias = b1[col];
#pragma unroll
            for (int r = 0; r < 4; r++) {
                float v = acc[i][j][r] + bias;
                v = fmaxf(v, 0.0f);
                hid[(size_t)(row0 + r) * HIDDEN + col] = (bf16)v;
            }
        }
    }
}

// ---------------- GEMM2: out = hid @ W2 + b2 + x, fp32 out ----------------
__global__ __launch_bounds__(256) void gemm2_kernel(const bf16* __restrict__ Hd,
                                                    const bf16* __restrict__ Wt,
                                                    const float* __restrict__ b2,
                                                    const float* __restrict__ x,
                                                    float* __restrict__ out) {
    __shared__ __align__(16) bf16 As[128 * 32];
    __shared__ __align__(16) bf16 Bs[128 * 32];
    const int t = threadIdx.x;
    const int wave = t >> 6, lane = t & 63;
    const int quad = lane >> 4, l16 = lane & 15;
    const int wm = (wave & 1) << 6, wn = (wave >> 1) << 6;
    const int bm = blockIdx.x, bn = blockIdx.y;

    f32x4 acc[4][4] = {};

    const char* Ag = (const char*)Hd + (size_t)bm * 128 * (HIDDEN * 2);
    const char* Bg = (const char*)Wt + (size_t)bn * 128 * (HIDDEN * 2);
    const int srow = t >> 2, scc = t & 3;
    const size_t rowoff = (size_t)srow * (HIDDEN * 2) + scc * 16;
    char* Al = (char*)As + t * 16;
    char* Bl = (char*)Bs + t * 16;

    for (int k0 = 0; k0 < HIDDEN; k0 += 32) {
        __syncthreads();
        const char* a0 = Ag + rowoff + k0 * 2;
        glds16(a0, Al);
        glds16(a0 + (size_t)64 * (HIDDEN * 2), Al + 4096);
        const char* b0 = Bg + rowoff + k0 * 2;
        glds16(b0, Bl);
        glds16(b0 + (size_t)64 * (HIDDEN * 2), Bl + 4096);
        __syncthreads();
        bf16x8 a[4], b[4];
#pragma unroll
        for (int i = 0; i < 4; i++) a[i] = *(const bf16x8*)&As[(wm + i * 16 + l16) * 32 + quad * 8];
#pragma unroll
        for (int i = 0; i < 4; i++) b[i] = *(const bf16x8*)&Bs[(wn + i * 16 + l16) * 32 + quad * 8];
#pragma unroll
        for (int i = 0; i < 4; i++)
#pragma unroll
            for (int j = 0; j < 4; j++)
                acc[i][j] = __builtin_amdgcn_mfma_f32_16x16x32_bf16(a[i], b[j], acc[i][j], 0, 0, 0);
    }
#pragma unroll
    for (int i = 0; i < 4; i++) {
        int row0 = bm * 128 + wm + i * 16 + quad * 4;
#pragma unroll
        for (int j = 0; j < 4; j++) {
            int col = bn * 128 + wn + j * 16 + l16;
            float bias = b2[col];
#pragma unroll
            for (int r = 0; r < 4; r++) {
                int row = row0 + r;
                if (row < N_NODES) {
                    size_t idx = (size_t)row * NODE_F + col;
                    out[idx] = acc[i][j][r] + bias + x[idx];
                }
            }
        }
    }
}

extern "C" void kernel_launch(void* const* d_in, const int* in_sizes, int n_in,
                              void* d_out, int out_size, void* d_ws, size_t ws_size,
                              hipStream_t stream) {
    const float* x         = (const float*)d_in[0];
    const float* edge_attr = (const float*)d_in[1];
    const float* u         = (const float*)d_in[2];
    const float* W1        = (const float*)d_in[3];
    const float* b1        = (const float*)d_in[4];
    const float* W2        = (const float*)d_in[5];
    const float* b2        = (const float*)d_in[6];
    const int*   edge_index= (const int*)d_in[7];
    const int*   batch     = (const int*)d_in[8];
    float*       out       = (float*)d_out;

    char* ws = (char*)d_ws;
    bf16* H    = (bf16*)(ws + H_OFF);
    bf16* hid  = (bf16*)(ws + HID_OFF);
    bf16* W1t  = (bf16*)(ws + W1T_OFF);
    bf16* W2t  = (bf16*)(ws + W2T_OFF);
    int*  deg  = (int*)(ws + DEG_OFF);
    int*  cur  = (int*)(ws + CUR_OFF);
    int*  start= (int*)(ws + START_OFF);
    int*  eids = (int*)(ws + EIDS_OFF);

    const int* col = edge_index + N_EDGES;    // edge_index[1][:]

    // 1) zero deg + cursor (contiguous)
    hipMemsetAsync(ws + DEG_OFF, 0, DEG_BYTES + CUR_BYTES, stream);
    // 2) degree histogram
    hist_kernel<<<(N_EDGES + 255) / 256, 256, 0, stream>>>(col, deg);
    // 3) exclusive scan -> start
    scan_kernel<<<1, 1024, 0, stream>>>(deg, start);
    // 4) scatter edge ids into CSR buckets
    scatter_kernel<<<(N_EDGES + 255) / 256, 256, 0, stream>>>(col, start, cur, eids);
    // 5) build bf16 H (fused segment sum/max/mean + concat)
    build_h_kernel<<<M_PAD, 128, 0, stream>>>(x, edge_attr, u, batch, start, eids, H);
    // 6) weights -> bf16 transposed
    convert_w_kernel<<<(HIDDEN * MLP_IN + 255) / 256, 256, 0, stream>>>(W1, W2, W1t, W2t);
    // 7) GEMM1 + bias + relu
    gemm1_kernel<<<dim3(M_PAD / 128, HIDDEN / 128), 256, 0, stream>>>(H, W1t, b1, hid);
    // 8) GEMM2 + bias + residual
    gemm2_kernel<<<dim3(M_PAD / 128, NODE_F / 128), 256, 0, stream>>>(hid, W2t, b2, x, out);
}

// Round 2
// 879.368 us; speedup vs baseline: 1.0587x; 1.0587x over previous
//
#include <hip/hip_runtime.h>
#include <stdint.h>

#define N_NODES 50000
#define N_EDGES 800000
#define EDGE_F  96
#define NODE_F  256
#define GLOB_F  64
#define HIDDEN  1024
#define MLP_IN  608           // 256 + 3*96 + 64
#define M_PAD   50048         // 391 * 128, padded row count for GEMM tiles

typedef __bf16 bf16;
typedef __bf16 bf16x8 __attribute__((ext_vector_type(8)));
typedef float  f32x4  __attribute__((ext_vector_type(4)));

typedef __attribute__((address_space(1))) unsigned int gu32;
typedef __attribute__((address_space(3))) unsigned int lu32;

__device__ __forceinline__ void glds16(const void* g, void* l) {
    __builtin_amdgcn_global_load_lds((const gu32*)g, (lu32*)l, 16, 0, 0);
}

// ---------------- workspace layout (bytes) ----------------
static constexpr size_t H_OFF    = 0;
static constexpr size_t H_BYTES  = (size_t)M_PAD * MLP_IN * 2;
static constexpr size_t HID_OFF  = H_OFF + H_BYTES;
static constexpr size_t HID_BYTES= (size_t)M_PAD * HIDDEN * 2;
static constexpr size_t W1T_OFF  = HID_OFF + HID_BYTES;
static constexpr size_t W1T_BYTES= (size_t)HIDDEN * MLP_IN * 2;
static constexpr size_t W2T_OFF  = W1T_OFF + W1T_BYTES;
static constexpr size_t W2T_BYTES= (size_t)NODE_F * HIDDEN * 2;
static constexpr size_t DEG_OFF  = W2T_OFF + W2T_BYTES;
static constexpr size_t DEG_BYTES= 200192;
static constexpr size_t CUR_OFF  = DEG_OFF + DEG_BYTES;
static constexpr size_t CUR_BYTES= 200192;
static constexpr size_t START_OFF= CUR_OFF + CUR_BYTES;
static constexpr size_t START_BYTES = 200192;
static constexpr size_t EIDS_OFF = START_OFF + START_BYTES;
static constexpr size_t EIDS_BYTES = (size_t)N_EDGES * 4;

// ---------------- CSR build ----------------
__global__ __launch_bounds__(256) void hist_kernel(const int* __restrict__ col,
                                                   int* __restrict__ deg) {
    int e = blockIdx.x * 256 + threadIdx.x;
    if (e < N_EDGES) atomicAdd(&deg[col[e]], 1);
}

__global__ __launch_bounds__(1024) void scan_kernel(const int* __restrict__ deg,
                                                    int* __restrict__ start) {
    __shared__ int partial[1024];
    const int t = threadIdx.x;
    const int CH = 49;
    int base = t * CH;
    int s = 0;
    for (int i = 0; i < CH; i++) {
        int idx = base + i;
        if (idx < N_NODES) s += deg[idx];
    }
    partial[t] = s;
    __syncthreads();
    for (int off = 1; off < 1024; off <<= 1) {
        int v = (t >= off) ? partial[t - off] : 0;
        __syncthreads();
        partial[t] += v;
        __syncthreads();
    }
    int run = (t == 0) ? 0 : partial[t - 1];
    for (int i = 0; i < CH; i++) {
        int idx = base + i;
        if (idx < N_NODES) { start[idx] = run; run += deg[idx]; }
    }
    if (t == 1023) start[N_NODES] = run;
}

__global__ __launch_bounds__(256) void scatter_kernel(const int* __restrict__ col,
                                                      const int* __restrict__ start,
                                                      int* __restrict__ cursor,
                                                      int* __restrict__ eids) {
    int e = blockIdx.x * 256 + threadIdx.x;
    if (e < N_EDGES) {
        int c = col[e];
        int p = start[c] + atomicAdd(&cursor[c], 1);
        eids[p] = e;
    }
}

// ---------------- build H = [x | sum | max | mean | u[batch]] in bf16 ----------------
// One node per 128-thread block. eids staged in LDS (breaks the load chain),
// edge gather unrolled x4 (4 independent 384B row reads in flight).
#define BH_CHUNK 128
__global__ __launch_bounds__(128) void build_h_kernel(const float* __restrict__ x,
                                                      const float* __restrict__ edge_attr,
                                                      const float* __restrict__ u,
                                                      const int* __restrict__ batch,
                                                      const int* __restrict__ start,
                                                      const int* __restrict__ eids,
                                                      bf16* __restrict__ H) {
    const int n = blockIdx.x;
    const int t = threadIdx.x;
    bf16* row = H + (size_t)n * MLP_IN;
    if (n >= N_NODES) {                       // pad rows -> zeros
        for (int c = t; c < MLP_IN; c += 128) row[c] = (bf16)0.0f;
        return;
    }
    // x copy: 64 lanes x float4
    if (t < 64) {
        float4 v = ((const float4*)(x + (size_t)n * NODE_F))[t];
        row[t * 4 + 0] = (bf16)v.x;
        row[t * 4 + 1] = (bf16)v.y;
        row[t * 4 + 2] = (bf16)v.z;
        row[t * 4 + 3] = (bf16)v.w;
    } else {
        int g = batch[n];
        row[544 + (t - 64)] = (bf16)u[g * GLOB_F + (t - 64)];
    }

    __shared__ int se[BH_CHUNK];
    const int s0 = start[n], s1 = start[n + 1];
    float sm = 0.0f, mx = -3.0e38f;
    for (int base = s0; base < s1; base += BH_CHUNK) {
        const int cnt = min(BH_CHUNK, s1 - base);
        __syncthreads();
        if (t < cnt) se[t] = eids[base + t];
        __syncthreads();
        if (t < EDGE_F) {
            int i = 0;
            for (; i + 4 <= cnt; i += 4) {
                float v0 = edge_attr[(size_t)se[i + 0] * EDGE_F + t];
                float v1 = edge_attr[(size_t)se[i + 1] * EDGE_F + t];
                float v2 = edge_attr[(size_t)se[i + 2] * EDGE_F + t];
                float v3 = edge_attr[(size_t)se[i + 3] * EDGE_F + t];
                sm += (v0 + v1) + (v2 + v3);
                mx = fmaxf(mx, fmaxf(fmaxf(v0, v1), fmaxf(v2, v3)));
            }
            for (; i < cnt; i++) {
                float v = edge_attr[(size_t)se[i] * EDGE_F + t];
                sm += v;
                mx = fmaxf(mx, v);
            }
        }
    }
    if (t < EDGE_F) {
        int d = s1 - s0;
        if (d == 0) mx = 0.0f;
        float mean = sm / fmaxf((float)d, 1.0f);
        row[256 + t] = (bf16)sm;
        row[352 + t] = (bf16)mx;
        row[448 + t] = (bf16)mean;
    }
}

// ---------------- weights: fp32 [K][N] -> bf16 transposed [N][K] ----------------
__global__ __launch_bounds__(256) void convert_w_kernel(const float* __restrict__ W1,
                                                        const float* __restrict__ W2,
                                                        bf16* __restrict__ W1t,
                                                        bf16* __restrict__ W2t) {
    int i = blockIdx.x * 256 + threadIdx.x;
    if (i < HIDDEN * MLP_IN) {
        int n = i / MLP_IN, k = i - n * MLP_IN;
        W1t[i] = (bf16)W1[(size_t)k * HIDDEN + n];
    }
    if (i < NODE_F * HIDDEN) {
        int n = i / HIDDEN, k = i - n * HIDDEN;
        W2t[i] = (bf16)W2[(size_t)k * NODE_F + n];
    }
}

// ---------------- GEMM1: hid = relu(H @ W1 + b1), bf16 out ----------------
__global__ __launch_bounds__(256) void gemm1_kernel(const bf16* __restrict__ H,
                                                    const bf16* __restrict__ Wt,
                                                    const float* __restrict__ b1,
                                                    bf16* __restrict__ hid) {
    __shared__ __align__(16) bf16 As[128 * 32];
    __shared__ __align__(16) bf16 Bs[128 * 32];
    const int t = threadIdx.x;
    const int wave = t >> 6, lane = t & 63;
    const int quad = lane >> 4, l16 = lane & 15;
    const int wm = (wave & 1) << 6, wn = (wave >> 1) << 6;
    const int bm = blockIdx.x, bn = blockIdx.y;

    f32x4 acc[4][4] = {};

    const char* Ag = (const char*)H  + (size_t)bm * 128 * (MLP_IN * 2);
    const char* Bg = (const char*)Wt + (size_t)bn * 128 * (MLP_IN * 2);
    const int srow = t >> 2, scc = t & 3;
    const size_t rowoff = (size_t)srow * (MLP_IN * 2) + scc * 16;
    char* Al = (char*)As + t * 16;
    char* Bl = (char*)Bs + t * 16;

    for (int k0 = 0; k0 < MLP_IN; k0 += 32) {
        __syncthreads();
        const char* a0 = Ag + rowoff + k0 * 2;
        glds16(a0, Al);
        glds16(a0 + (size_t)64 * (MLP_IN * 2), Al + 4096);
        const char* b0 = Bg + rowoff + k0 * 2;
        glds16(b0, Bl);
        glds16(b0 + (size_t)64 * (MLP_IN * 2), Bl + 4096);
        __syncthreads();
        bf16x8 a[4], b[4];
#pragma unroll
        for (int i = 0; i < 4; i++) a[i] = *(const bf16x8*)&As[(wm + i * 16 + l16) * 32 + quad * 8];
#pragma unroll
        for (int i = 0; i < 4; i++) b[i] = *(const bf16x8*)&Bs[(wn + i * 16 + l16) * 32 + quad * 8];
#pragma unroll
        for (int i = 0; i < 4; i++)
#pragma unroll
            for (int j = 0; j < 4; j++)
                acc[i][j] = __builtin_amdgcn_mfma_f32_16x16x32_bf16(a[i], b[j], acc[i][j], 0, 0, 0);
    }
#pragma unroll
    for (int i = 0; i < 4; i++) {
        int row0 = bm * 128 + wm + i * 16 + quad * 4;
#pragma unroll
        for (int j = 0; j < 4; j++) {
            int col = bn * 128 + wn + j * 16 + l16;
            float bias = b1[col];
#pragma unroll
            for (int r = 0; r < 4; r++) {
                float v = acc[i][j][r] + bias;
                v = fmaxf(v, 0.0f);
                hid[(size_t)(row0 + r) * HIDDEN + col] = (bf16)v;
            }
        }
    }
}

// ---------------- GEMM2: out = hid @ W2 + b2 + x, fp32 out ----------------
__global__ __launch_bounds__(256) void gemm2_kernel(const bf16* __restrict__ Hd,
                                                    const bf16* __restrict__ Wt,
                                                    const float* __restrict__ b2,
                                                    const float* __restrict__ x,
                                                    float* __restrict__ out) {
    __shared__ __align__(16) bf16 As[128 * 32];
    __shared__ __align__(16) bf16 Bs[128 * 32];
    const int t = threadIdx.x;
    const int wave = t >> 6, lane = t & 63;
    const int quad = lane >> 4, l16 = lane & 15;
    const int wm = (wave & 1) << 6, wn = (wave >> 1) << 6;
    const int bm = blockIdx.x, bn = blockIdx.y;

    f32x4 acc[4][4] = {};

    const char* Ag = (const char*)Hd + (size_t)bm * 128 * (HIDDEN * 2);
    const char* Bg = (const char*)Wt + (size_t)bn * 128 * (HIDDEN * 2);
    const int srow = t >> 2, scc = t & 3;
    const size_t rowoff = (size_t)srow * (HIDDEN * 2) + scc * 16;
    char* Al = (char*)As + t * 16;
    char* Bl = (char*)Bs + t * 16;

    for (int k0 = 0; k0 < HIDDEN; k0 += 32) {
        __syncthreads();
        const char* a0 = Ag + rowoff + k0 * 2;
        glds16(a0, Al);
        glds16(a0 + (size_t)64 * (HIDDEN * 2), Al + 4096);
        const char* b0 = Bg + rowoff + k0 * 2;
        glds16(b0, Bl);
        glds16(b0 + (size_t)64 * (HIDDEN * 2), Bl + 4096);
        __syncthreads();
        bf16x8 a[4], b[4];
#pragma unroll
        for (int i = 0; i < 4; i++) a[i] = *(const bf16x8*)&As[(wm + i * 16 + l16) * 32 + quad * 8];
#pragma unroll
        for (int i = 0; i < 4; i++) b[i] = *(const bf16x8*)&Bs[(wn + i * 16 + l16) * 32 + quad * 8];
#pragma unroll
        for (int i = 0; i < 4; i++)
#pragma unroll
            for (int j = 0; j < 4; j++)
                acc[i][j] = __builtin_amdgcn_mfma_f32_16x16x32_bf16(a[i], b[j], acc[i][j], 0, 0, 0);
    }
#pragma unroll
    for (int i = 0; i < 4; i++) {
        int row0 = bm * 128 + wm + i * 16 + quad * 4;
#pragma unroll
        for (int j = 0; j < 4; j++) {
            int col = bn * 128 + wn + j * 16 + l16;
            float bias = b2[col];
#pragma unroll
            for (int r = 0; r < 4; r++) {
                int row = row0 + r;
                if (row < N_NODES) {
                    size_t idx = (size_t)row * NODE_F + col;
                    out[idx] = acc[i][j][r] + bias + x[idx];
                }
            }
        }
    }
}

extern "C" void kernel_launch(void* const* d_in, const int* in_sizes, int n_in,
                              void* d_out, int out_size, void* d_ws, size_t ws_size,
                              hipStream_t stream) {
    const float* x         = (const float*)d_in[0];
    const float* edge_attr = (const float*)d_in[1];
    const float* u         = (const float*)d_in[2];
    const float* W1        = (const float*)d_in[3];
    const float* b1        = (const float*)d_in[4];
    const float* W2        = (const float*)d_in[5];
    const float* b2        = (const float*)d_in[6];
    const int*   edge_index= (const int*)d_in[7];
    const int*   batch     = (const int*)d_in[8];
    float*       out       = (float*)d_out;

    char* ws = (char*)d_ws;
    bf16* H    = (bf16*)(ws + H_OFF);
    bf16* hid  = (bf16*)(ws + HID_OFF);
    bf16* W1t  = (bf16*)(ws + W1T_OFF);
    bf16* W2t  = (bf16*)(ws + W2T_OFF);
    int*  deg  = (int*)(ws + DEG_OFF);
    int*  cur  = (int*)(ws + CUR_OFF);
    int*  start= (int*)(ws + START_OFF);
    int*  eids = (int*)(ws + EIDS_OFF);

    const int* col = edge_index + N_EDGES;

    hipMemsetAsync(ws + DEG_OFF, 0, DEG_BYTES + CUR_BYTES, stream);
    hist_kernel<<<(N_EDGES + 255) / 256, 256, 0, stream>>>(col, deg);
    scan_kernel<<<1, 1024, 0, stream>>>(deg, start);
    scatter_kernel<<<(N_EDGES + 255) / 256, 256, 0, stream>>>(col, start, cur, eids);
    build_h_kernel<<<M_PAD, 128, 0, stream>>>(x, edge_attr, u, batch, start, eids, H);
    convert_w_kernel<<<(HIDDEN * MLP_IN + 255) / 256, 256, 0, stream>>>(W1, W2, W1t, W2t);
    gemm1_kernel<<<dim3(M_PAD / 128, HIDDEN / 128), 256, 0, stream>>>(H, W1t, b1, hid);
    gemm2_kernel<<<dim3(M_PAD / 128, NODE_F / 128), 256, 0, stream>>>(hid, W2t, b2, x, out);
}

// Round 3
// 792.593 us; speedup vs baseline: 1.1746x; 1.1095x over previous
//
#include <hip/hip_runtime.h>
#include <stdint.h>

#define N_NODES 50000
#define N_EDGES 800000
#define EDGE_F  96
#define NODE_F  256
#define GLOB_F  64
#define HIDDEN  1024
#define MLP_IN  608           // 256 + 3*96 + 64
#define M_PAD   50048         // 391 * 128
#define SCAN_BLOCKS 196       // 196*256 = 50176 >= 50000

typedef __bf16 bf16;
typedef __bf16 bf16x8 __attribute__((ext_vector_type(8)));
typedef float  f32x4  __attribute__((ext_vector_type(4)));

typedef __attribute__((address_space(1))) unsigned int gu32;
typedef __attribute__((address_space(3))) unsigned int lu32;

__device__ __forceinline__ void glds16(const void* g, void* l) {
    __builtin_amdgcn_global_load_lds((const gu32*)g, (lu32*)l, 16, 0, 0);
}

// ---------------- workspace layout (bytes) ----------------
static constexpr size_t H_OFF    = 0;
static constexpr size_t H_BYTES  = (size_t)M_PAD * MLP_IN * 2;
static constexpr size_t HID_OFF  = H_OFF + H_BYTES;
static constexpr size_t HID_BYTES= (size_t)M_PAD * HIDDEN * 2;
static constexpr size_t W1T_OFF  = HID_OFF + HID_BYTES;
static constexpr size_t W1T_BYTES= (size_t)HIDDEN * MLP_IN * 2;
static constexpr size_t W2T_OFF  = W1T_OFF + W1T_BYTES;
static constexpr size_t W2T_BYTES= (size_t)NODE_F * HIDDEN * 2;
static constexpr size_t DEG_OFF  = W2T_OFF + W2T_BYTES;
static constexpr size_t DEG_BYTES= 200192;
static constexpr size_t CUR_OFF  = DEG_OFF + DEG_BYTES;
static constexpr size_t CUR_BYTES= 200192;
static constexpr size_t START_OFF= CUR_OFF + CUR_BYTES;
static constexpr size_t START_BYTES = 200192;
static constexpr size_t EIDS_OFF = START_OFF + START_BYTES;
static constexpr size_t EIDS_BYTES = (size_t)N_EDGES * 4;
static constexpr size_t BSUM_OFF = EIDS_OFF + EIDS_BYTES;
static constexpr size_t BSUM_BYTES = 1024;
static constexpr size_t BOFF_OFF = BSUM_OFF + BSUM_BYTES;

// ---------------- CSR build ----------------
__global__ __launch_bounds__(256) void hist_kernel(const int* __restrict__ col,
                                                   int* __restrict__ deg) {
    int e = blockIdx.x * 256 + threadIdx.x;
    if (e < N_EDGES) atomicAdd(&deg[col[e]], 1);
}

// 3-phase parallel exclusive scan over deg[0..N_NODES) -> start
__global__ __launch_bounds__(256) void scan_phase1(const int* __restrict__ deg,
                                                   int* __restrict__ start,
                                                   int* __restrict__ bsum) {
    __shared__ int sc[256];
    const int t = threadIdx.x, b = blockIdx.x;
    const int idx = b * 256 + t;
    int v = (idx < N_NODES) ? deg[idx] : 0;
    sc[t] = v;
    __syncthreads();
    for (int off = 1; off < 256; off <<= 1) {
        int add = (t >= off) ? sc[t - off] : 0;
        __syncthreads();
        sc[t] += add;
        __syncthreads();
    }
    if (idx < N_NODES) start[idx] = sc[t] - v;   // exclusive within block
    if (t == 255) bsum[b] = sc[255];
}

__global__ __launch_bounds__(256) void scan_phase2(int* __restrict__ bsum,
                                                   int* __restrict__ boff,
                                                   int* __restrict__ start) {
    __shared__ int sc[256];
    const int t = threadIdx.x;
    int v = (t < SCAN_BLOCKS) ? bsum[t] : 0;
    sc[t] = v;
    __syncthreads();
    for (int off = 1; off < 256; off <<= 1) {
        int add = (t >= off) ? sc[t - off] : 0;
        __syncthreads();
        sc[t] += add;
        __syncthreads();
    }
    if (t < SCAN_BLOCKS) boff[t] = sc[t] - v;    // exclusive block offsets
    if (t == 255) start[N_NODES] = sc[255];      // == N_EDGES
}

__global__ __launch_bounds__(256) void scan_phase3(int* __restrict__ start,
                                                   const int* __restrict__ boff) {
    const int idx = blockIdx.x * 256 + threadIdx.x;
    if (idx < N_NODES) start[idx] += boff[blockIdx.x];
}

__global__ __launch_bounds__(256) void scatter_kernel(const int* __restrict__ col,
                                                      const int* __restrict__ start,
                                                      int* __restrict__ cursor,
                                                      int* __restrict__ eids) {
    int e = blockIdx.x * 256 + threadIdx.x;
    if (e < N_EDGES) {
        int c = col[e];
        int p = start[c] + atomicAdd(&cursor[c], 1);
        eids[p] = e;
    }
}

// ---------------- build H = [x | sum | max | mean | u[batch]] in bf16 ----------------
// One node per 128-thread block; eids staged in LDS; gather unrolled x8
// (8 independent 384B edge-row reads in flight per feature-thread).
#define BH_CHUNK 128
__global__ __launch_bounds__(128) void build_h_kernel(const float* __restrict__ x,
                                                      const float* __restrict__ edge_attr,
                                                      const float* __restrict__ u,
                                                      const int* __restrict__ batch,
                                                      const int* __restrict__ start,
                                                      const int* __restrict__ eids,
                                                      bf16* __restrict__ H) {
    const int n = blockIdx.x;
    const int t = threadIdx.x;
    bf16* row = H + (size_t)n * MLP_IN;
    if (n >= N_NODES) {
        for (int c = t; c < MLP_IN; c += 128) row[c] = (bf16)0.0f;
        return;
    }
    if (t < 64) {
        float4 v = ((const float4*)(x + (size_t)n * NODE_F))[t];
        row[t * 4 + 0] = (bf16)v.x;
        row[t * 4 + 1] = (bf16)v.y;
        row[t * 4 + 2] = (bf16)v.z;
        row[t * 4 + 3] = (bf16)v.w;
    } else {
        int g = batch[n];
        row[544 + (t - 64)] = (bf16)u[g * GLOB_F + (t - 64)];
    }

    __shared__ int se[BH_CHUNK];
    const int s0 = start[n], s1 = start[n + 1];
    float sm = 0.0f, mx = -3.0e38f;
    for (int base = s0; base < s1; base += BH_CHUNK) {
        const int cnt = min(BH_CHUNK, s1 - base);
        __syncthreads();
        if (t < cnt) se[t] = eids[base + t];
        __syncthreads();
        if (t < EDGE_F) {
            int i = 0;
            for (; i + 8 <= cnt; i += 8) {
                float v0 = edge_attr[(size_t)se[i + 0] * EDGE_F + t];
                float v1 = edge_attr[(size_t)se[i + 1] * EDGE_F + t];
                float v2 = edge_attr[(size_t)se[i + 2] * EDGE_F + t];
                float v3 = edge_attr[(size_t)se[i + 3] * EDGE_F + t];
                float v4 = edge_attr[(size_t)se[i + 4] * EDGE_F + t];
                float v5 = edge_attr[(size_t)se[i + 5] * EDGE_F + t];
                float v6 = edge_attr[(size_t)se[i + 6] * EDGE_F + t];
                float v7 = edge_attr[(size_t)se[i + 7] * EDGE_F + t];
                sm += ((v0 + v1) + (v2 + v3)) + ((v4 + v5) + (v6 + v7));
                float m01 = fmaxf(v0, v1), m23 = fmaxf(v2, v3);
                float m45 = fmaxf(v4, v5), m67 = fmaxf(v6, v7);
                mx = fmaxf(mx, fmaxf(fmaxf(m01, m23), fmaxf(m45, m67)));
            }
            for (; i + 2 <= cnt; i += 2) {
                float v0 = edge_attr[(size_t)se[i + 0] * EDGE_F + t];
                float v1 = edge_attr[(size_t)se[i + 1] * EDGE_F + t];
                sm += v0 + v1;
                mx = fmaxf(mx, fmaxf(v0, v1));
            }
            if (i < cnt) {
                float v = edge_attr[(size_t)se[i] * EDGE_F + t];
                sm += v;
                mx = fmaxf(mx, v);
            }
        }
    }
    if (t < EDGE_F) {
        int d = s1 - s0;
        if (d == 0) mx = 0.0f;
        float mean = sm / fmaxf((float)d, 1.0f);
        row[256 + t] = (bf16)sm;
        row[352 + t] = (bf16)mx;
        row[448 + t] = (bf16)mean;
    }
}

// ---------------- coalesced transpose: W [K][N] f32 -> Wt [N][K] bf16 ----------------
// 32x32 LDS tile (+1 pad); K,N multiples of 32 here (608,1024,256).
__global__ __launch_bounds__(256) void transpose_kernel(const float* __restrict__ W,
                                                        bf16* __restrict__ Wt,
                                                        int K, int N) {
    __shared__ float tile[32][33];
    const int tx = threadIdx.x & 31, ty = threadIdx.x >> 5;   // 32 x 8
    const int n0 = blockIdx.x * 32, k0 = blockIdx.y * 32;
#pragma unroll
    for (int r = 0; r < 4; r++)
        tile[ty + 8 * r][tx] = W[(size_t)(k0 + ty + 8 * r) * N + (n0 + tx)];
    __syncthreads();
#pragma unroll
    for (int r = 0; r < 4; r++)
        Wt[(size_t)(n0 + ty + 8 * r) * K + (k0 + tx)] = (bf16)tile[tx][ty + 8 * r];
}

// ---------------- GEMM1: hid = relu(H @ W1 + b1), bf16 out ----------------
__global__ __launch_bounds__(256) void gemm1_kernel(const bf16* __restrict__ H,
                                                    const bf16* __restrict__ Wt,
                                                    const float* __restrict__ b1,
                                                    bf16* __restrict__ hid) {
    __shared__ __align__(16) bf16 As[128 * 32];
    __shared__ __align__(16) bf16 Bs[128 * 32];
    const int t = threadIdx.x;
    const int wave = t >> 6, lane = t & 63;
    const int quad = lane >> 4, l16 = lane & 15;
    const int wm = (wave & 1) << 6, wn = (wave >> 1) << 6;
    const int bm = blockIdx.x, bn = blockIdx.y;

    f32x4 acc[4][4] = {};

    const char* Ag = (const char*)H  + (size_t)bm * 128 * (MLP_IN * 2);
    const char* Bg = (const char*)Wt + (size_t)bn * 128 * (MLP_IN * 2);
    const int srow = t >> 2, scc = t & 3;
    const size_t rowoff = (size_t)srow * (MLP_IN * 2) + scc * 16;
    char* Al = (char*)As + t * 16;
    char* Bl = (char*)Bs + t * 16;

    for (int k0 = 0; k0 < MLP_IN; k0 += 32) {
        __syncthreads();
        const char* a0 = Ag + rowoff + k0 * 2;
        glds16(a0, Al);
        glds16(a0 + (size_t)64 * (MLP_IN * 2), Al + 4096);
        const char* b0 = Bg + rowoff + k0 * 2;
        glds16(b0, Bl);
        glds16(b0 + (size_t)64 * (MLP_IN * 2), Bl + 4096);
        __syncthreads();
        bf16x8 a[4], b[4];
#pragma unroll
        for (int i = 0; i < 4; i++) a[i] = *(const bf16x8*)&As[(wm + i * 16 + l16) * 32 + quad * 8];
#pragma unroll
        for (int i = 0; i < 4; i++) b[i] = *(const bf16x8*)&Bs[(wn + i * 16 + l16) * 32 + quad * 8];
#pragma unroll
        for (int i = 0; i < 4; i++)
#pragma unroll
            for (int j = 0; j < 4; j++)
                acc[i][j] = __builtin_amdgcn_mfma_f32_16x16x32_bf16(a[i], b[j], acc[i][j], 0, 0, 0);
    }
#pragma unroll
    for (int i = 0; i < 4; i++) {
        int row0 = bm * 128 + wm + i * 16 + quad * 4;
#pragma unroll
        for (int j = 0; j < 4; j++) {
            int col = bn * 128 + wn + j * 16 + l16;
            float bias = b1[col];
#pragma unroll
            for (int r = 0; r < 4; r++) {
                float v = acc[i][j][r] + bias;
                v = fmaxf(v, 0.0f);
                hid[(size_t)(row0 + r) * HIDDEN + col] = (bf16)v;
            }
        }
    }
}

// ---------------- GEMM2: out = hid @ W2 + b2 + x, fp32 out ----------------
__global__ __launch_bounds__(256) void gemm2_kernel(const bf16* __restrict__ Hd,
                                                    const bf16* __restrict__ Wt,
                                                    const float* __restrict__ b2,
                                                    const float* __restrict__ x,
                                                    float* __restrict__ out) {
    __shared__ __align__(16) bf16 As[128 * 32];
    __shared__ __align__(16) bf16 Bs[128 * 32];
    const int t = threadIdx.x;
    const int wave = t >> 6, lane = t & 63;
    const int quad = lane >> 4, l16 = lane & 15;
    const int wm = (wave & 1) << 6, wn = (wave >> 1) << 6;
    const int bm = blockIdx.x, bn = blockIdx.y;

    f32x4 acc[4][4] = {};

    const char* Ag = (const char*)Hd + (size_t)bm * 128 * (HIDDEN * 2);
    const char* Bg = (const char*)Wt + (size_t)bn * 128 * (HIDDEN * 2);
    const int srow = t >> 2, scc = t & 3;
    const size_t rowoff = (size_t)srow * (HIDDEN * 2) + scc * 16;
    char* Al = (char*)As + t * 16;
    char* Bl = (char*)Bs + t * 16;

    for (int k0 = 0; k0 < HIDDEN; k0 += 32) {
        __syncthreads();
        const char* a0 = Ag + rowoff + k0 * 2;
        glds16(a0, Al);
        glds16(a0 + (size_t)64 * (HIDDEN * 2), Al + 4096);
        const char* b0 = Bg + rowoff + k0 * 2;
        glds16(b0, Bl);
        glds16(b0 + (size_t)64 * (HIDDEN * 2), Bl + 4096);
        __syncthreads();
        bf16x8 a[4], b[4];
#pragma unroll
        for (int i = 0; i < 4; i++) a[i] = *(const bf16x8*)&As[(wm + i * 16 + l16) * 32 + quad * 8];
#pragma unroll
        for (int i = 0; i < 4; i++) b[i] = *(const bf16x8*)&Bs[(wn + i * 16 + l16) * 32 + quad * 8];
#pragma unroll
        for (int i = 0; i < 4; i++)
#pragma unroll
            for (int j = 0; j < 4; j++)
                acc[i][j] = __builtin_amdgcn_mfma_f32_16x16x32_bf16(a[i], b[j], acc[i][j], 0, 0, 0);
    }
#pragma unroll
    for (int i = 0; i < 4; i++) {
        int row0 = bm * 128 + wm + i * 16 + quad * 4;
#pragma unroll
        for (int j = 0; j < 4; j++) {
            int col = bn * 128 + wn + j * 16 + l16;
            float bias = b2[col];
#pragma unroll
            for (int r = 0; r < 4; r++) {
                int row = row0 + r;
                if (row < N_NODES) {
                    size_t idx = (size_t)row * NODE_F + col;
                    out[idx] = acc[i][j][r] + bias + x[idx];
                }
            }
        }
    }
}

extern "C" void kernel_launch(void* const* d_in, const int* in_sizes, int n_in,
                              void* d_out, int out_size, void* d_ws, size_t ws_size,
                              hipStream_t stream) {
    const float* x         = (const float*)d_in[0];
    const float* edge_attr = (const float*)d_in[1];
    const float* u         = (const float*)d_in[2];
    const float* W1        = (const float*)d_in[3];
    const float* b1        = (const float*)d_in[4];
    const float* W2        = (const float*)d_in[5];
    const float* b2        = (const float*)d_in[6];
    const int*   edge_index= (const int*)d_in[7];
    const int*   batch     = (const int*)d_in[8];
    float*       out       = (float*)d_out;

    char* ws = (char*)d_ws;
    bf16* H    = (bf16*)(ws + H_OFF);
    bf16* hid  = (bf16*)(ws + HID_OFF);
    bf16* W1t  = (bf16*)(ws + W1T_OFF);
    bf16* W2t  = (bf16*)(ws + W2T_OFF);
    int*  deg  = (int*)(ws + DEG_OFF);
    int*  cur  = (int*)(ws + CUR_OFF);
    int*  start= (int*)(ws + START_OFF);
    int*  eids = (int*)(ws + EIDS_OFF);
    int*  bsum = (int*)(ws + BSUM_OFF);
    int*  boff = (int*)(ws + BOFF_OFF);

    const int* col = edge_index + N_EDGES;

    hipMemsetAsync(ws + DEG_OFF, 0, DEG_BYTES + CUR_BYTES, stream);
    hist_kernel<<<(N_EDGES + 255) / 256, 256, 0, stream>>>(col, deg);
    scan_phase1<<<SCAN_BLOCKS, 256, 0, stream>>>(deg, start, bsum);
    scan_phase2<<<1, 256, 0, stream>>>(bsum, boff, start);
    scan_phase3<<<SCAN_BLOCKS, 256, 0, stream>>>(start, boff);
    scatter_kernel<<<(N_EDGES + 255) / 256, 256, 0, stream>>>(col, start, cur, eids);
    build_h_kernel<<<M_PAD, 128, 0, stream>>>(x, edge_attr, u, batch, start, eids, H);
    transpose_kernel<<<dim3(HIDDEN / 32, MLP_IN / 32), 256, 0, stream>>>(W1, W1t, MLP_IN, HIDDEN);
    transpose_kernel<<<dim3(NODE_F / 32, HIDDEN / 32), 256, 0, stream>>>(W2, W2t, HIDDEN, NODE_F);
    gemm1_kernel<<<dim3(M_PAD / 128, HIDDEN / 128), 256, 0, stream>>>(H, W1t, b1, hid);
    gemm2_kernel<<<dim3(M_PAD / 128, NODE_F / 128), 256, 0, stream>>>(hid, W2t, b2, x, out);
}